// Round 14
// baseline (1436.126 us; speedup 1.0000x reference)
//
#include <hip/hip_runtime.h>

#define NN 50000
#define TT 24
#define HH 64
#define HORZ 12
#define EE 1600000

#define GP 256          // scatter partitions
#define EP (EE / GP)    // 6250 edges per partition (exact)
#define BK 784          // dst buckets of 64 nodes (782 used, padded)
#define NBG (BK * GP)   // 200704 cells
#define SCB (NBG / 512) // 392 scan blocks (exact)
#define BKA ((NN + 63) / 64)  // 782 agg blocks

#define L2E 1.44269504088896340736f

typedef __attribute__((ext_vector_type(8))) _Float16 f16x8;
typedef __attribute__((ext_vector_type(4))) _Float16 f16x4;
typedef __attribute__((ext_vector_type(4))) float f32x4;

// ---------- P1 histogram + merged fragment build (exp2-prescaled GRU weights) ----------
// frag layout per weight: [nf][kf(2)][lane(64)][8]; frag = W[16nf+(l&15)][32kf+8(l>>4)+j].
// whh tiles nf 0-7 (r,z) scaled by L2E; nf 8-11 (n) by 2*L2E. l1/l2/fc unscaled.
__global__ __launch_bounds__(256) void p1_frags_kernel(
    const int* __restrict__ dst, int* __restrict__ hist,
    const float* __restrict__ whh, const float* __restrict__ g1,
    const float* __restrict__ g2, const float* __restrict__ fcw,
    _Float16* __restrict__ frag) {
  int bid = blockIdx.x;
  if (bid >= GP) {  // fragment-build blocks
    int idx = (bid - GP) * 256 + threadIdx.x;
    if (idx >= 21504) return;
    const float* W;
    int rows, li;
    float sc = 1.f;
    if (idx < 12288) {
      W = whh; rows = 192; li = idx;
      sc = ((li >> 10) >= 8) ? 2.f * L2E : L2E;
    }
    else if (idx < 16384) { W = g1; rows = 64; li = idx - 12288; }
    else if (idx < 20480) { W = g2; rows = 64; li = idx - 16384; }
    else { W = fcw; rows = HORZ; li = idx - 20480; }
    int j = li & 7;
    int l = (li >> 3) & 63;
    int kf = (li >> 9) & 1;
    int nf = li >> 10;
    int col = 16 * nf + (l & 15);
    int k = 32 * kf + 8 * (l >> 4) + j;
    frag[idx] = (col < rows) ? (_Float16)(W[col * 64 + k] * sc) : (_Float16)0.f;
    return;
  }
  __shared__ int h[BK];
  int tid = threadIdx.x, g = bid;
  for (int b = tid; b < BK; b += 256) h[b] = 0;
  __syncthreads();
  int e0 = g * EP;
  for (int i = tid; i < EP; i += 256) atomicAdd(&h[dst[e0 + i] >> 6], 1);
  __syncthreads();
  for (int b = tid; b < BK; b += 256) hist[b * GP + g] = h[b];
}

// ---------- scan over NBG cells (exact 392x512) ----------
__global__ void scanA_kernel(const int* __restrict__ v, int* __restrict__ part) {
  __shared__ int s[512];
  int i = blockIdx.x * 512 + threadIdx.x;
  s[threadIdx.x] = v[i];
  __syncthreads();
  for (int off = 256; off > 0; off >>= 1) {
    if (threadIdx.x < off) s[threadIdx.x] += s[threadIdx.x + off];
    __syncthreads();
  }
  if (threadIdx.x == 0) part[blockIdx.x] = s[0];
}

__global__ void scanB_kernel(int* __restrict__ part) {
  __shared__ int s[512];
  int t = threadIdx.x;
  int v = (t < SCB) ? part[t] : 0;
  s[t] = v;
  __syncthreads();
  for (int off = 1; off < 512; off <<= 1) {
    int a = s[t];
    int b = (t >= off) ? s[t - off] : 0;
    __syncthreads();
    s[t] = a + b;
    __syncthreads();
  }
  if (t < SCB) part[t] = s[t] - v;  // exclusive
}

// in-place: cellbase[i] = exclusive_prefix(hist)[i]
__global__ void scanC_kernel(int* __restrict__ cellbase, const int* __restrict__ part) {
  __shared__ int s[2][512];
  int tid = threadIdx.x;
  int i = blockIdx.x * 512 + tid;
  int x = cellbase[i];
  s[0][tid] = x;
  __syncthreads();
  int cur = 0;
  for (int off = 1; off < 512; off <<= 1) {
    int nxt = cur ^ 1;
    int val = s[cur][tid] + ((tid >= off) ? s[cur][tid - off] : 0);
    s[nxt][tid] = val;
    __syncthreads();
    cur = nxt;
  }
  cellbase[i] = part[blockIdx.x] + s[cur][tid] - x;
  if (i == 0) cellbase[NBG] = EE;
}

// ---------- P2: bucketed scatter of packed records, LDS cursors ----------
__global__ __launch_bounds__(256) void p2_scatter_kernel(
    const int* __restrict__ src, const int* __restrict__ dst,
    const int* __restrict__ cellbase, unsigned int* __restrict__ rec) {
  __shared__ int cur[BK];
  int tid = threadIdx.x, g = blockIdx.x;
  for (int b = tid; b < BK; b += 256) cur[b] = cellbase[b * GP + g];
  __syncthreads();
  int e0 = g * EP;
  for (int i = tid; i < EP; i += 256) {
    int e = e0 + i;
    int d = dst[e];
    int s = src[e];
    int p = atomicAdd(&cur[d >> 6], 1);
    rec[p] = ((unsigned)(d & 63) << 16) | (unsigned)s;
  }
}

// ---------- per-bucket degree -> dinv ----------
__global__ __launch_bounds__(256) void deg_kernel(const unsigned int* __restrict__ rec,
                                                  const int* __restrict__ cellbase,
                                                  float* __restrict__ dinv) {
  __shared__ int cnt[64];
  int b = blockIdx.x, tid = threadIdx.x;
  if (tid < 64) cnt[tid] = 0;
  __syncthreads();
  int e0 = cellbase[b * GP], e1 = cellbase[(b + 1) * GP];
  for (int e = e0 + tid; e < e1; e += 256) atomicAdd(&cnt[rec[e] >> 16], 1);
  __syncthreads();
  if (tid < 64) {
    int n = b * 64 + tid;
    if (n < NN) dinv[n] = rsqrtf((float)(cnt[tid] + 1));  // +1 self loop
  }
}

// ---------- MFMA GRU, operand-swapped (A=weights, B=h), exp2-prescaled + fused linear1 ----------
// gh^T = W_hh · h^T. Lane (c=lane&15, q=lane>>4) of wave w owns node c,
// H-dims 16w+4q+r (r=0..3). Per step: 1 ds_write_b64, 2 ds_read_b128, 1 broadcast ds_read_b32.
// Gates (prescaled, raw v_exp_f32): sigm = rcp(1+exp2(-acc)), tanh = 1-2*rcp(1+exp2(acc)).
__global__ __launch_bounds__(256, 5) void gru_kernel(
    const float* __restrict__ x, const float* __restrict__ w_ih,
    const float* __restrict__ b_ih, const float* __restrict__ b_hh,
    const _Float16* __restrict__ wfrag, const _Float16* __restrict__ l1f,
    const float* __restrict__ dinv, _Float16* __restrict__ hw) {
  __shared__ __align__(16) _Float16 sh[2][16][72];  // [buf][node][dim], 144B rows
  __shared__ __align__(16) float xs[TT][16];        // [t][node] transposed

  const int tid = threadIdx.x;
  const int lane = tid & 63;
  const int w = tid >> 6;   // H-dim quarter 0..3
  const int c = lane & 15;  // node
  const int q = lane >> 4;

  // A-fragments (prescaled weights) for gate tiles {w, 4+w, 8+w}, kf 0..1
  f16x8 Ar0 = *(const f16x8*)&wfrag[(((w)*2 + 0) * 64 + lane) * 8];
  f16x8 Ar1 = *(const f16x8*)&wfrag[(((w)*2 + 1) * 64 + lane) * 8];
  f16x8 Az0 = *(const f16x8*)&wfrag[(((4 + w) * 2 + 0) * 64 + lane) * 8];
  f16x8 Az1 = *(const f16x8*)&wfrag[(((4 + w) * 2 + 1) * 64 + lane) * 8];
  f16x8 An0 = *(const f16x8*)&wfrag[(((8 + w) * 2 + 0) * 64 + lane) * 8];
  f16x8 An1 = *(const f16x8*)&wfrag[(((8 + w) * 2 + 1) * 64 + lane) * 8];

  // per-lane gate constants for dims dd = 16w + 4q + r, exp2-prescaled
  float wir[4], wiz[4], win[4], arb[4], azb[4], binc[4], bhnc[4];
#pragma unroll
  for (int r = 0; r < 4; ++r) {
    int dd = 16 * w + 4 * q + r;
    wir[r] = w_ih[dd] * L2E;
    wiz[r] = w_ih[64 + dd] * L2E;
    win[r] = w_ih[128 + dd] * (2.f * L2E);
    arb[r] = (b_ih[dd] + b_hh[dd]) * L2E;
    azb[r] = (b_ih[64 + dd] + b_hh[64 + dd]) * L2E;
    binc[r] = b_ih[128 + dd] * (2.f * L2E);
    bhnc[r] = b_hh[128 + dd] * (2.f * L2E);
  }

  const int base = blockIdx.x * 16;  // 3125 blocks exact

  // stage x transposed: xs[t][node_local]
  for (int i = tid; i < 16 * TT; i += 256) {
    int nl = i / TT;
    int t = i - nl * TT;
    xs[t][nl] = x[(base + nl) * TT + t];
  }
  __syncthreads();

  float hreg[4] = {0.f, 0.f, 0.f, 0.f};  // h[node c][16w+4q+r]

#pragma unroll 1
  for (int tp = 0; tp < TT / 2; ++tp) {
#pragma unroll
    for (int half = 0; half < 2; ++half) {  // static buffer indices
      const int t = 2 * tp + half;
      f32x4 ar = (f32x4){arb[0], arb[1], arb[2], arb[3]};
      f32x4 az = (f32x4){azb[0], azb[1], azb[2], azb[3]};
      f32x4 an = (f32x4){bhnc[0], bhnc[1], bhnc[2], bhnc[3]};
      if (t > 0) {
        const _Float16* S = &sh[half ^ 1][0][0];
        f16x8 b0 = *(const f16x8*)&S[c * 72 + 8 * q];        // h B-frag k=0..31
        f16x8 b1 = *(const f16x8*)&S[c * 72 + 32 + 8 * q];   // k=32..63
        ar = __builtin_amdgcn_mfma_f32_16x16x32_f16(Ar0, b0, ar, 0, 0, 0);
        az = __builtin_amdgcn_mfma_f32_16x16x32_f16(Az0, b0, az, 0, 0, 0);
        an = __builtin_amdgcn_mfma_f32_16x16x32_f16(An0, b0, an, 0, 0, 0);
        ar = __builtin_amdgcn_mfma_f32_16x16x32_f16(Ar1, b1, ar, 0, 0, 0);
        az = __builtin_amdgcn_mfma_f32_16x16x32_f16(Az1, b1, az, 0, 0, 0);
        an = __builtin_amdgcn_mfma_f32_16x16x32_f16(An1, b1, an, 0, 0, 0);
      }
      float xv = xs[t][c];  // broadcast read, uniform over q
      f16x4 hpack;
#pragma unroll
      for (int r = 0; r < 4; ++r) {
        float rg = __builtin_amdgcn_rcpf(1.f + __builtin_amdgcn_exp2f(-fmaf(xv, wir[r], ar[r])));
        float zg = __builtin_amdgcn_rcpf(1.f + __builtin_amdgcn_exp2f(-fmaf(xv, wiz[r], az[r])));
        float sn = fmaf(rg, an[r], fmaf(xv, win[r], binc[r]));
        float nn = fmaf(-2.f, __builtin_amdgcn_rcpf(1.f + __builtin_amdgcn_exp2f(sn)), 1.f);
        float hn = nn + zg * (hreg[r] - nn);
        hreg[r] = hn;
        hpack[r] = (_Float16)hn;
      }
      *(f16x4*)&sh[half][c][16 * w + 4 * q] = hpack;  // one ds_write_b64
      __syncthreads();
    }
  }

  // fused linear1: hw[n] = f16( dinv[n] * (gc1 · h^T) ); final h in sh[1]
  {
    f16x8 L0 = *(const f16x8*)&l1f[((w * 2 + 0) * 64 + lane) * 8];
    f16x8 L1 = *(const f16x8*)&l1f[((w * 2 + 1) * 64 + lane) * 8];
    const _Float16* S = &sh[1][0][0];
    f16x8 b0 = *(const f16x8*)&S[c * 72 + 8 * q];
    f16x8 b1 = *(const f16x8*)&S[c * 72 + 32 + 8 * q];
    f32x4 acc = (f32x4){0.f, 0.f, 0.f, 0.f};
    acc = __builtin_amdgcn_mfma_f32_16x16x32_f16(L0, b0, acc, 0, 0, 0);
    acc = __builtin_amdgcn_mfma_f32_16x16x32_f16(L1, b1, acc, 0, 0, 0);
    float dn = dinv[base + c];
    f16x4 opack;
#pragma unroll
    for (int r = 0; r < 4; ++r) opack[r] = (_Float16)(acc[r] * dn);
    *(f16x4*)&hw[(base + c) * 64 + 16 * w + 4 * q] = opack;  // one 8B store
  }
}

// ---------- edge-parallel agg (bucket block, 16 waves, LDS f32 atomics) + fused linear2 ----------
__global__ __launch_bounds__(1024, 4) void agg_lin_kernel(
    const _Float16* __restrict__ hwp, const float* __restrict__ dinv,
    const unsigned int* __restrict__ rec, const int* __restrict__ cellbase,
    const float* __restrict__ bias, const _Float16* __restrict__ l2f,
    _Float16* __restrict__ out) {
  __shared__ float sacc[4096];                   // 16 KB fp32 accumulators
  __shared__ __align__(16) _Float16 h1[64][72];  // relu'd rows for MFMA, 144B stride
  int tid = threadIdx.x, b = blockIdx.x;
  int wv = tid >> 6, lane = tid & 63;
  // init with self loop (hwp already dinv-scaled)
  for (int idx = tid; idx < 4096; idx += 1024) {
    int row = idx >> 6, col = idx & 63;
    int n = b * 64 + row;
    sacc[idx] = (n < NN) ? (float)hwp[n * 64 + col] : 0.f;
  }
  __syncthreads();
  int e0 = cellbase[b * GP], e1 = cellbase[(b + 1) * GP];
  for (int eb = e0 + wv * 8; eb < e1; eb += 128) {
    unsigned rr[8];
    float vv[8];
#pragma unroll
    for (int k = 0; k < 8; ++k) rr[k] = (eb + k < e1) ? rec[eb + k] : 0u;
#pragma unroll
    for (int k = 0; k < 8; ++k)
      vv[k] = (eb + k < e1) ? (float)hwp[(rr[k] & 0xFFFFu) * 64 + lane] : 0.f;
#pragma unroll
    for (int k = 0; k < 8; ++k)
      atomicAdd(&sacc[(rr[k] >> 16) * 64 + lane], vv[k]);
  }
  __syncthreads();
  // dinv + bias + relu -> f16 rows
  for (int idx = tid; idx < 4096; idx += 1024) {
    int row = idx >> 6, col = idx & 63;
    int n = b * 64 + row;
    float v = (n < NN) ? (sacc[idx] * dinv[n] + bias[col]) : 0.f;
    h1[row][col] = (_Float16)(v > 0.f ? v : 0.f);
  }
  __syncthreads();
  // linear2 + dinv: wave (g=wv>>2, wq=wv&3) computes rows [16g,16g+16) x dims [16wq,16wq+16)
  int g = wv >> 2, wq = wv & 3;
  int c = lane & 15, q = lane >> 4;
  f16x8 B0 = *(const f16x8*)&l2f[((wq * 2 + 0) * 64 + lane) * 8];
  f16x8 B1 = *(const f16x8*)&l2f[((wq * 2 + 1) * 64 + lane) * 8];
  f16x8 a0 = *(const f16x8*)&h1[16 * g + c][8 * q];
  f16x8 a1 = *(const f16x8*)&h1[16 * g + c][32 + 8 * q];
  f32x4 acc = (f32x4){0.f, 0.f, 0.f, 0.f};
  acc = __builtin_amdgcn_mfma_f32_16x16x32_f16(a0, B0, acc, 0, 0, 0);
  acc = __builtin_amdgcn_mfma_f32_16x16x32_f16(a1, B1, acc, 0, 0, 0);
#pragma unroll
  for (int r = 0; r < 4; ++r) {
    int n = b * 64 + 16 * g + 4 * q + r;
    if (n < NN) out[n * 64 + 16 * wq + c] = (_Float16)(acc[r] * dinv[n]);
  }
}

// ---------- edge-parallel agg (bucket block) + fused final FC ----------
__global__ __launch_bounds__(1024, 4) void agg_fc_kernel(
    const _Float16* __restrict__ hwp, const float* __restrict__ dinv,
    const unsigned int* __restrict__ rec, const int* __restrict__ cellbase,
    const float* __restrict__ bias, const _Float16* __restrict__ fcf,
    const float* __restrict__ fcb, float* __restrict__ out) {
  __shared__ float sacc[4096];
  __shared__ __align__(16) _Float16 h1[64][72];
  int tid = threadIdx.x, b = blockIdx.x;
  int wv = tid >> 6, lane = tid & 63;
  for (int idx = tid; idx < 4096; idx += 1024) {
    int row = idx >> 6, col = idx & 63;
    int n = b * 64 + row;
    sacc[idx] = (n < NN) ? (float)hwp[n * 64 + col] : 0.f;
  }
  __syncthreads();
  int e0 = cellbase[b * GP], e1 = cellbase[(b + 1) * GP];
  for (int eb = e0 + wv * 8; eb < e1; eb += 128) {
    unsigned rr[8];
    float vv[8];
#pragma unroll
    for (int k = 0; k < 8; ++k) rr[k] = (eb + k < e1) ? rec[eb + k] : 0u;
#pragma unroll
    for (int k = 0; k < 8; ++k)
      vv[k] = (eb + k < e1) ? (float)hwp[(rr[k] & 0xFFFFu) * 64 + lane] : 0.f;
#pragma unroll
    for (int k = 0; k < 8; ++k)
      atomicAdd(&sacc[(rr[k] >> 16) * 64 + lane], vv[k]);
  }
  __syncthreads();
  for (int idx = tid; idx < 4096; idx += 1024) {
    int row = idx >> 6, col = idx & 63;
    int n = b * 64 + row;
    float v = (n < NN) ? (sacc[idx] * dinv[n] + bias[col]) : 0.f;
    h1[row][col] = (_Float16)(v > 0.f ? v : 0.f);
  }
  __syncthreads();
  // fc: waves 0..3 handle node group g=wv
  if (wv < 4) {
    int g = wv;
    int c = lane & 15, q = lane >> 4;
    f16x8 B0 = *(const f16x8*)&fcf[(0 * 64 + lane) * 8];
    f16x8 B1 = *(const f16x8*)&fcf[(1 * 64 + lane) * 8];
    f16x8 a0 = *(const f16x8*)&h1[16 * g + c][8 * q];
    f16x8 a1 = *(const f16x8*)&h1[16 * g + c][32 + 8 * q];
    float bc = (c < HORZ) ? fcb[c] : 0.f;
    f32x4 acc = (f32x4){bc, bc, bc, bc};
    acc = __builtin_amdgcn_mfma_f32_16x16x32_f16(a0, B0, acc, 0, 0, 0);
    acc = __builtin_amdgcn_mfma_f32_16x16x32_f16(a1, B1, acc, 0, 0, 0);
    if (c < HORZ) {
#pragma unroll
      for (int r = 0; r < 4; ++r) {
        int n = b * 64 + 16 * g + 4 * q + r;
        if (n < NN) out[n * HORZ + c] = acc[r];
      }
    }
  }
}

extern "C" void kernel_launch(void* const* d_in, const int* in_sizes, int n_in,
                              void* d_out, int out_size, void* d_ws, size_t ws_size,
                              hipStream_t stream) {
  (void)in_sizes; (void)n_in; (void)out_size; (void)ws_size;
  const float* x = (const float*)d_in[0];
  const int* edge_index = (const int*)d_in[1];
  const float* w_ih = (const float*)d_in[2];
  const float* w_hh = (const float*)d_in[3];
  const float* b_ih = (const float*)d_in[4];
  const float* b_hh = (const float*)d_in[5];
  const float* gc1_w = (const float*)d_in[6];
  const float* gc1_b = (const float*)d_in[7];
  const float* gc2_w = (const float*)d_in[8];
  const float* gc2_b = (const float*)d_in[9];
  const float* fc_w = (const float*)d_in[10];
  const float* fc_b = (const float*)d_in[11];
  float* out = (float*)d_out;

  // workspace layout (all regions 16B-aligned)
  char* ws = (char*)d_ws;
  _Float16* wfrag = (_Float16*)ws;                 // 12288 halves
  _Float16* l1f = wfrag + 12288;                   // 4096
  _Float16* l2f = l1f + 4096;                      // 4096
  _Float16* fcf = l2f + 4096;                      // 1024  -> 43008 B
  _Float16* hw1 = (_Float16*)(ws + 43008);         // NN*64 f16 = 6.4 MB
  _Float16* hw2 = hw1 + NN * 64;                   // NN*64 f16 = 6.4 MB
  float* dinv = (float*)(hw2 + NN * 64);           // NN f32
  int* cellbase = (int*)(dinv + NN);               // NBG+4 ints
  int* part = cellbase + NBG + 4;                  // 512 ints
  unsigned int* rec = (unsigned int*)(part + 512); // EE u32 = 6.4 MB

  const int* esrc = edge_index;
  const int* edst = edge_index + EE;

  // graph build first (gru's fused linear1 needs dinv)
  p1_frags_kernel<<<GP + 84, 256, 0, stream>>>(edst, cellbase, w_hh, gc1_w, gc2_w, fc_w, wfrag);
  scanA_kernel<<<SCB, 512, 0, stream>>>(cellbase, part);
  scanB_kernel<<<1, 512, 0, stream>>>(part);
  scanC_kernel<<<SCB, 512, 0, stream>>>(cellbase, part);
  p2_scatter_kernel<<<GP, 256, 0, stream>>>(esrc, edst, cellbase, rec);
  deg_kernel<<<BK, 256, 0, stream>>>(rec, cellbase, dinv);

  gru_kernel<<<NN / 16, 256, 0, stream>>>(x, w_ih, b_ih, b_hh, wfrag, l1f, dinv, hw1);
  agg_lin_kernel<<<BKA, 1024, 0, stream>>>(hw1, dinv, rec, cellbase, gc1_b, l2f, hw2);
  agg_fc_kernel<<<BKA, 1024, 0, stream>>>(hw2, dinv, rec, cellbase, gc2_b, fcf, fc_b, out);
}

// Round 15
// 227.650 us; speedup vs baseline: 6.3085x; 6.3085x over previous
//
#include <hip/hip_runtime.h>

#define NN 50000
#define TT 24
#define HH 64
#define HORZ 12
#define EE 1600000

#define GP 256          // scatter partitions
#define EP (EE / GP)    // 6250 edges per partition (exact)
#define BK 784          // dst buckets of 64 nodes (782 used, padded)
#define NBG (BK * GP)   // 200704 cells
#define SCB (NBG / 512) // 392 scan blocks (exact)
#define BKA ((NN + 63) / 64)  // 782 agg blocks

#define L2E 1.44269504088896340736f

typedef __attribute__((ext_vector_type(8))) _Float16 f16x8;
typedef __attribute__((ext_vector_type(4))) _Float16 f16x4;
typedef __attribute__((ext_vector_type(4))) float f32x4;

// ---------- P1 histogram + merged fragment build (exp2-prescaled GRU weights) ----------
// frag layout per weight: [nf][kf(2)][lane(64)][8]; frag = W[16nf+(l&15)][32kf+8(l>>4)+j].
// whh tiles nf 0-7 (r,z) scaled by L2E; nf 8-11 (n) by 2*L2E. l1/l2/fc unscaled.
__global__ __launch_bounds__(256) void p1_frags_kernel(
    const int* __restrict__ dst, int* __restrict__ hist,
    const float* __restrict__ whh, const float* __restrict__ g1,
    const float* __restrict__ g2, const float* __restrict__ fcw,
    _Float16* __restrict__ frag) {
  int bid = blockIdx.x;
  if (bid >= GP) {  // fragment-build blocks
    int idx = (bid - GP) * 256 + threadIdx.x;
    if (idx >= 21504) return;
    const float* W;
    int rows, li;
    float sc = 1.f;
    if (idx < 12288) {
      W = whh; rows = 192; li = idx;
      sc = ((li >> 10) >= 8) ? 2.f * L2E : L2E;
    }
    else if (idx < 16384) { W = g1; rows = 64; li = idx - 12288; }
    else if (idx < 20480) { W = g2; rows = 64; li = idx - 16384; }
    else { W = fcw; rows = HORZ; li = idx - 20480; }
    int j = li & 7;
    int l = (li >> 3) & 63;
    int kf = (li >> 9) & 1;
    int nf = li >> 10;
    int col = 16 * nf + (l & 15);
    int k = 32 * kf + 8 * (l >> 4) + j;
    frag[idx] = (col < rows) ? (_Float16)(W[col * 64 + k] * sc) : (_Float16)0.f;
    return;
  }
  __shared__ int h[BK];
  int tid = threadIdx.x, g = bid;
  for (int b = tid; b < BK; b += 256) h[b] = 0;
  __syncthreads();
  int e0 = g * EP;
  for (int i = tid; i < EP; i += 256) atomicAdd(&h[dst[e0 + i] >> 6], 1);
  __syncthreads();
  for (int b = tid; b < BK; b += 256) hist[b * GP + g] = h[b];
}

// ---------- scan over NBG cells (exact 392x512) ----------
__global__ void scanA_kernel(const int* __restrict__ v, int* __restrict__ part) {
  __shared__ int s[512];
  int i = blockIdx.x * 512 + threadIdx.x;
  s[threadIdx.x] = v[i];
  __syncthreads();
  for (int off = 256; off > 0; off >>= 1) {
    if (threadIdx.x < off) s[threadIdx.x] += s[threadIdx.x + off];
    __syncthreads();
  }
  if (threadIdx.x == 0) part[blockIdx.x] = s[0];
}

__global__ void scanB_kernel(int* __restrict__ part) {
  __shared__ int s[512];
  int t = threadIdx.x;
  int v = (t < SCB) ? part[t] : 0;
  s[t] = v;
  __syncthreads();
  for (int off = 1; off < 512; off <<= 1) {
    int a = s[t];
    int b = (t >= off) ? s[t - off] : 0;
    __syncthreads();
    s[t] = a + b;
    __syncthreads();
  }
  if (t < SCB) part[t] = s[t] - v;  // exclusive
}

// in-place: cellbase[i] = exclusive_prefix(hist)[i]
__global__ void scanC_kernel(int* __restrict__ cellbase, const int* __restrict__ part) {
  __shared__ int s[2][512];
  int tid = threadIdx.x;
  int i = blockIdx.x * 512 + tid;
  int x = cellbase[i];
  s[0][tid] = x;
  __syncthreads();
  int cur = 0;
  for (int off = 1; off < 512; off <<= 1) {
    int nxt = cur ^ 1;
    int val = s[cur][tid] + ((tid >= off) ? s[cur][tid - off] : 0);
    s[nxt][tid] = val;
    __syncthreads();
    cur = nxt;
  }
  cellbase[i] = part[blockIdx.x] + s[cur][tid] - x;
  if (i == 0) cellbase[NBG] = EE;
}

// ---------- P2: bucketed scatter of packed records, LDS cursors ----------
__global__ __launch_bounds__(256) void p2_scatter_kernel(
    const int* __restrict__ src, const int* __restrict__ dst,
    const int* __restrict__ cellbase, unsigned int* __restrict__ rec) {
  __shared__ int cur[BK];
  int tid = threadIdx.x, g = blockIdx.x;
  for (int b = tid; b < BK; b += 256) cur[b] = cellbase[b * GP + g];
  __syncthreads();
  int e0 = g * EP;
  for (int i = tid; i < EP; i += 256) {
    int e = e0 + i;
    int d = dst[e];
    int s = src[e];
    int p = atomicAdd(&cur[d >> 6], 1);
    rec[p] = ((unsigned)(d & 63) << 16) | (unsigned)s;
  }
}

// ---------- second-level sort: bucket records -> node-ordered ushort CSR + row_start + dinv ----------
__global__ __launch_bounds__(256) void sort2_kernel(
    const unsigned int* __restrict__ rec, const int* __restrict__ cellbase,
    unsigned short* __restrict__ csr, int* __restrict__ row_start,
    float* __restrict__ dinv) {
  __shared__ int cnt[64];
  __shared__ int cur[64];
  int b = blockIdx.x, tid = threadIdx.x;
  if (tid < 64) cnt[tid] = 0;
  __syncthreads();
  int e0 = cellbase[b * GP], e1 = cellbase[(b + 1) * GP];
  for (int e = e0 + tid; e < e1; e += 256) atomicAdd(&cnt[rec[e] >> 16], 1);
  __syncthreads();
  if (tid < 64) {  // wave 0: 6-step shfl scan replaces 64-iter serial prefix
    int v = cnt[tid];
    int inc = v;
#pragma unroll
    for (int off = 1; off < 64; off <<= 1) {
      int y = __shfl_up(inc, off);
      if (tid >= off) inc += y;
    }
    int p = e0 + inc - v;  // exclusive prefix + bucket base
    cur[tid] = p;
    int n = b * 64 + tid;
    if (n <= NN) row_start[n] = p;
    if (n < NN) dinv[n] = rsqrtf((float)(v + 1));  // +1 self loop
  }
  __syncthreads();  // cur visible to all waves before atomic mutation
  for (int e = e0 + tid; e < e1; e += 256) {
    unsigned int r = rec[e];
    int p = atomicAdd(&cur[r >> 16], 1);
    csr[p] = (unsigned short)(r & 0xFFFFu);
  }
}

// ---------- MFMA GRU, operand-swapped (A=weights, B=h), exp2-prescaled + fused linear1 ----------
// gh^T = W_hh · h^T. Lane (c=lane&15, q=lane>>4) of wave w owns node c,
// H-dims 16w+4q+r (r=0..3). Per step: 1 ds_write_b64, 2 ds_read_b128, 1 broadcast ds_read_b32.
// Gates (prescaled, raw v_exp_f32): sigm = rcp(1+exp2(-acc)), tanh = 1-2*rcp(1+exp2(acc)).
__global__ __launch_bounds__(256, 5) void gru_kernel(
    const float* __restrict__ x, const float* __restrict__ w_ih,
    const float* __restrict__ b_ih, const float* __restrict__ b_hh,
    const _Float16* __restrict__ wfrag, const _Float16* __restrict__ l1f,
    const float* __restrict__ dinv, _Float16* __restrict__ hw) {
  __shared__ __align__(16) _Float16 sh[2][16][72];  // [buf][node][dim], 144B rows
  __shared__ __align__(16) float xs[TT][16];        // [t][node] transposed

  const int tid = threadIdx.x;
  const int lane = tid & 63;
  const int w = tid >> 6;   // H-dim quarter 0..3
  const int c = lane & 15;  // node
  const int q = lane >> 4;

  // A-fragments (prescaled weights) for gate tiles {w, 4+w, 8+w}, kf 0..1
  f16x8 Ar0 = *(const f16x8*)&wfrag[(((w)*2 + 0) * 64 + lane) * 8];
  f16x8 Ar1 = *(const f16x8*)&wfrag[(((w)*2 + 1) * 64 + lane) * 8];
  f16x8 Az0 = *(const f16x8*)&wfrag[(((4 + w) * 2 + 0) * 64 + lane) * 8];
  f16x8 Az1 = *(const f16x8*)&wfrag[(((4 + w) * 2 + 1) * 64 + lane) * 8];
  f16x8 An0 = *(const f16x8*)&wfrag[(((8 + w) * 2 + 0) * 64 + lane) * 8];
  f16x8 An1 = *(const f16x8*)&wfrag[(((8 + w) * 2 + 1) * 64 + lane) * 8];

  // per-lane gate constants for dims dd = 16w + 4q + r, exp2-prescaled
  float wir[4], wiz[4], win[4], arb[4], azb[4], binc[4], bhnc[4];
#pragma unroll
  for (int r = 0; r < 4; ++r) {
    int dd = 16 * w + 4 * q + r;
    wir[r] = w_ih[dd] * L2E;
    wiz[r] = w_ih[64 + dd] * L2E;
    win[r] = w_ih[128 + dd] * (2.f * L2E);
    arb[r] = (b_ih[dd] + b_hh[dd]) * L2E;
    azb[r] = (b_ih[64 + dd] + b_hh[64 + dd]) * L2E;
    binc[r] = b_ih[128 + dd] * (2.f * L2E);
    bhnc[r] = b_hh[128 + dd] * (2.f * L2E);
  }

  const int base = blockIdx.x * 16;  // 3125 blocks exact

  // stage x transposed: xs[t][node_local]
  for (int i = tid; i < 16 * TT; i += 256) {
    int nl = i / TT;
    int t = i - nl * TT;
    xs[t][nl] = x[(base + nl) * TT + t];
  }
  __syncthreads();

  float hreg[4] = {0.f, 0.f, 0.f, 0.f};  // h[node c][16w+4q+r]

#pragma unroll 1
  for (int tp = 0; tp < TT / 2; ++tp) {
#pragma unroll
    for (int half = 0; half < 2; ++half) {  // static buffer indices
      const int t = 2 * tp + half;
      f32x4 ar = (f32x4){arb[0], arb[1], arb[2], arb[3]};
      f32x4 az = (f32x4){azb[0], azb[1], azb[2], azb[3]};
      f32x4 an = (f32x4){bhnc[0], bhnc[1], bhnc[2], bhnc[3]};
      if (t > 0) {
        const _Float16* S = &sh[half ^ 1][0][0];
        f16x8 b0 = *(const f16x8*)&S[c * 72 + 8 * q];        // h B-frag k=0..31
        f16x8 b1 = *(const f16x8*)&S[c * 72 + 32 + 8 * q];   // k=32..63
        ar = __builtin_amdgcn_mfma_f32_16x16x32_f16(Ar0, b0, ar, 0, 0, 0);
        az = __builtin_amdgcn_mfma_f32_16x16x32_f16(Az0, b0, az, 0, 0, 0);
        an = __builtin_amdgcn_mfma_f32_16x16x32_f16(An0, b0, an, 0, 0, 0);
        ar = __builtin_amdgcn_mfma_f32_16x16x32_f16(Ar1, b1, ar, 0, 0, 0);
        az = __builtin_amdgcn_mfma_f32_16x16x32_f16(Az1, b1, az, 0, 0, 0);
        an = __builtin_amdgcn_mfma_f32_16x16x32_f16(An1, b1, an, 0, 0, 0);
      }
      float xv = xs[t][c];  // broadcast read, uniform over q
      f16x4 hpack;
#pragma unroll
      for (int r = 0; r < 4; ++r) {
        float rg = __builtin_amdgcn_rcpf(1.f + __builtin_amdgcn_exp2f(-fmaf(xv, wir[r], ar[r])));
        float zg = __builtin_amdgcn_rcpf(1.f + __builtin_amdgcn_exp2f(-fmaf(xv, wiz[r], az[r])));
        float sn = fmaf(rg, an[r], fmaf(xv, win[r], binc[r]));
        float nn = fmaf(-2.f, __builtin_amdgcn_rcpf(1.f + __builtin_amdgcn_exp2f(sn)), 1.f);
        float hn = nn + zg * (hreg[r] - nn);
        hreg[r] = hn;
        hpack[r] = (_Float16)hn;
      }
      *(f16x4*)&sh[half][c][16 * w + 4 * q] = hpack;  // one ds_write_b64
      __syncthreads();
    }
  }

  // fused linear1: hw[n] = f16( dinv[n] * (gc1 · h^T) ); final h in sh[1]
  {
    f16x8 L0 = *(const f16x8*)&l1f[((w * 2 + 0) * 64 + lane) * 8];
    f16x8 L1 = *(const f16x8*)&l1f[((w * 2 + 1) * 64 + lane) * 8];
    const _Float16* S = &sh[1][0][0];
    f16x8 b0 = *(const f16x8*)&S[c * 72 + 8 * q];
    f16x8 b1 = *(const f16x8*)&S[c * 72 + 32 + 8 * q];
    f32x4 acc = (f32x4){0.f, 0.f, 0.f, 0.f};
    acc = __builtin_amdgcn_mfma_f32_16x16x32_f16(L0, b0, acc, 0, 0, 0);
    acc = __builtin_amdgcn_mfma_f32_16x16x32_f16(L1, b1, acc, 0, 0, 0);
    float dn = dinv[base + c];
    f16x4 opack;
#pragma unroll
    for (int r = 0; r < 4; ++r) opack[r] = (_Float16)(acc[r] * dn);
    *(f16x4*)&hw[(base + c) * 64 + 16 * w + 4 * q] = opack;  // one 8B store
  }
}

// ---------- agg (bucket block, 16 waves, wave=4 nodes) + fused linear2 ----------
__global__ __launch_bounds__(1024, 4) void agg_lin_kernel(
    const _Float16* __restrict__ hwp, const float* __restrict__ dinv,
    const int* __restrict__ row_start, const unsigned short* __restrict__ csr,
    const float* __restrict__ bias, const _Float16* __restrict__ l2f,
    _Float16* __restrict__ out) {
  __shared__ __align__(16) _Float16 h1[64][72];  // relu'd agg rows, 144B stride
  int tid = threadIdx.x, b = blockIdx.x;
  int wv = tid >> 6, lane = tid & 63;
  float bl = bias[lane];
#pragma unroll 1
  for (int k = 0; k < 4; ++k) {
    int row = wv * 4 + k;
    int n = b * 64 + row;
    float v = 0.f;
    if (n < NN) {
      int e0 = row_start[n], e1 = row_start[n + 1];
      float a0 = (float)hwp[n * 64 + lane];  // self loop (dinv-scaled)
      float a1 = 0.f, a2 = 0.f, a3 = 0.f;
      int e = e0;
      for (; e < e1 && (e & 7); ++e) a0 += (float)hwp[(int)csr[e] * 64 + lane];
      for (; e + 16 <= e1; e += 16) {
        uint4 p0 = *(const uint4*)&csr[e];
        uint4 p1 = *(const uint4*)&csr[e + 8];
        a0 += (float)hwp[(p0.x & 0xFFFF) * 64 + lane];
        a1 += (float)hwp[(p0.x >> 16) * 64 + lane];
        a2 += (float)hwp[(p0.y & 0xFFFF) * 64 + lane];
        a3 += (float)hwp[(p0.y >> 16) * 64 + lane];
        a0 += (float)hwp[(p0.z & 0xFFFF) * 64 + lane];
        a1 += (float)hwp[(p0.z >> 16) * 64 + lane];
        a2 += (float)hwp[(p0.w & 0xFFFF) * 64 + lane];
        a3 += (float)hwp[(p0.w >> 16) * 64 + lane];
        a0 += (float)hwp[(p1.x & 0xFFFF) * 64 + lane];
        a1 += (float)hwp[(p1.x >> 16) * 64 + lane];
        a2 += (float)hwp[(p1.y & 0xFFFF) * 64 + lane];
        a3 += (float)hwp[(p1.y >> 16) * 64 + lane];
        a0 += (float)hwp[(p1.z & 0xFFFF) * 64 + lane];
        a1 += (float)hwp[(p1.z >> 16) * 64 + lane];
        a2 += (float)hwp[(p1.w & 0xFFFF) * 64 + lane];
        a3 += (float)hwp[(p1.w >> 16) * 64 + lane];
      }
      for (; e + 8 <= e1; e += 8) {
        uint4 pk = *(const uint4*)&csr[e];
        a0 += (float)hwp[(pk.x & 0xFFFF) * 64 + lane];
        a1 += (float)hwp[(pk.x >> 16) * 64 + lane];
        a2 += (float)hwp[(pk.y & 0xFFFF) * 64 + lane];
        a3 += (float)hwp[(pk.y >> 16) * 64 + lane];
        a0 += (float)hwp[(pk.z & 0xFFFF) * 64 + lane];
        a1 += (float)hwp[(pk.z >> 16) * 64 + lane];
        a2 += (float)hwp[(pk.w & 0xFFFF) * 64 + lane];
        a3 += (float)hwp[(pk.w >> 16) * 64 + lane];
      }
      for (; e < e1; ++e) a0 += (float)hwp[(int)csr[e] * 64 + lane];
      v = (a0 + a1 + a2 + a3) * dinv[n] + bl;
      v = v > 0.f ? v : 0.f;
    }
    h1[row][lane] = (_Float16)v;
  }
  __syncthreads();
  // linear2 + dinv: wave (g=wv>>2, wq=wv&3) computes rows [16g,16g+16) x dims [16wq,16wq+16)
  int g = wv >> 2, wq = wv & 3;
  int c = lane & 15, q = lane >> 4;
  f16x8 B0 = *(const f16x8*)&l2f[((wq * 2 + 0) * 64 + lane) * 8];
  f16x8 B1 = *(const f16x8*)&l2f[((wq * 2 + 1) * 64 + lane) * 8];
  f16x8 a0 = *(const f16x8*)&h1[16 * g + c][8 * q];
  f16x8 a1 = *(const f16x8*)&h1[16 * g + c][32 + 8 * q];
  f32x4 acc = (f32x4){0.f, 0.f, 0.f, 0.f};
  acc = __builtin_amdgcn_mfma_f32_16x16x32_f16(a0, B0, acc, 0, 0, 0);
  acc = __builtin_amdgcn_mfma_f32_16x16x32_f16(a1, B1, acc, 0, 0, 0);
#pragma unroll
  for (int r = 0; r < 4; ++r) {
    int n = b * 64 + 16 * g + 4 * q + r;
    if (n < NN) out[n * 64 + 16 * wq + c] = (_Float16)(acc[r] * dinv[n]);
  }
}

// ---------- agg (bucket block) + fused final FC ----------
__global__ __launch_bounds__(1024, 4) void agg_fc_kernel(
    const _Float16* __restrict__ hwp, const float* __restrict__ dinv,
    const int* __restrict__ row_start, const unsigned short* __restrict__ csr,
    const float* __restrict__ bias, const _Float16* __restrict__ fcf,
    const float* __restrict__ fcb, float* __restrict__ out) {
  __shared__ __align__(16) _Float16 h1[64][72];
  int tid = threadIdx.x, b = blockIdx.x;
  int wv = tid >> 6, lane = tid & 63;
  float bl = bias[lane];
#pragma unroll 1
  for (int k = 0; k < 4; ++k) {
    int row = wv * 4 + k;
    int n = b * 64 + row;
    float v = 0.f;
    if (n < NN) {
      int e0 = row_start[n], e1 = row_start[n + 1];
      float a0 = (float)hwp[n * 64 + lane];
      float a1 = 0.f, a2 = 0.f, a3 = 0.f;
      int e = e0;
      for (; e < e1 && (e & 7); ++e) a0 += (float)hwp[(int)csr[e] * 64 + lane];
      for (; e + 16 <= e1; e += 16) {
        uint4 p0 = *(const uint4*)&csr[e];
        uint4 p1 = *(const uint4*)&csr[e + 8];
        a0 += (float)hwp[(p0.x & 0xFFFF) * 64 + lane];
        a1 += (float)hwp[(p0.x >> 16) * 64 + lane];
        a2 += (float)hwp[(p0.y & 0xFFFF) * 64 + lane];
        a3 += (float)hwp[(p0.y >> 16) * 64 + lane];
        a0 += (float)hwp[(p0.z & 0xFFFF) * 64 + lane];
        a1 += (float)hwp[(p0.z >> 16) * 64 + lane];
        a2 += (float)hwp[(p0.w & 0xFFFF) * 64 + lane];
        a3 += (float)hwp[(p0.w >> 16) * 64 + lane];
        a0 += (float)hwp[(p1.x & 0xFFFF) * 64 + lane];
        a1 += (float)hwp[(p1.x >> 16) * 64 + lane];
        a2 += (float)hwp[(p1.y & 0xFFFF) * 64 + lane];
        a3 += (float)hwp[(p1.y >> 16) * 64 + lane];
        a0 += (float)hwp[(p1.z & 0xFFFF) * 64 + lane];
        a1 += (float)hwp[(p1.z >> 16) * 64 + lane];
        a2 += (float)hwp[(p1.w & 0xFFFF) * 64 + lane];
        a3 += (float)hwp[(p1.w >> 16) * 64 + lane];
      }
      for (; e + 8 <= e1; e += 8) {
        uint4 pk = *(const uint4*)&csr[e];
        a0 += (float)hwp[(pk.x & 0xFFFF) * 64 + lane];
        a1 += (float)hwp[(pk.x >> 16) * 64 + lane];
        a2 += (float)hwp[(pk.y & 0xFFFF) * 64 + lane];
        a3 += (float)hwp[(pk.y >> 16) * 64 + lane];
        a0 += (float)hwp[(pk.z & 0xFFFF) * 64 + lane];
        a1 += (float)hwp[(pk.z >> 16) * 64 + lane];
        a2 += (float)hwp[(pk.w & 0xFFFF) * 64 + lane];
        a3 += (float)hwp[(pk.w >> 16) * 64 + lane];
      }
      for (; e < e1; ++e) a0 += (float)hwp[(int)csr[e] * 64 + lane];
      v = (a0 + a1 + a2 + a3) * dinv[n] + bl;
      v = v > 0.f ? v : 0.f;
    }
    h1[row][lane] = (_Float16)v;
  }
  __syncthreads();
  // fc: waves 0..3 handle node group g=wv
  if (wv < 4) {
    int g = wv;
    int c = lane & 15, q = lane >> 4;
    f16x8 B0 = *(const f16x8*)&fcf[(0 * 64 + lane) * 8];
    f16x8 B1 = *(const f16x8*)&fcf[(1 * 64 + lane) * 8];
    f16x8 a0 = *(const f16x8*)&h1[16 * g + c][8 * q];
    f16x8 a1 = *(const f16x8*)&h1[16 * g + c][32 + 8 * q];
    float bc = (c < HORZ) ? fcb[c] : 0.f;
    f32x4 acc = (f32x4){bc, bc, bc, bc};
    acc = __builtin_amdgcn_mfma_f32_16x16x32_f16(a0, B0, acc, 0, 0, 0);
    acc = __builtin_amdgcn_mfma_f32_16x16x32_f16(a1, B1, acc, 0, 0, 0);
    if (c < HORZ) {
#pragma unroll
      for (int r = 0; r < 4; ++r) {
        int n = b * 64 + 16 * g + 4 * q + r;
        if (n < NN) out[n * HORZ + c] = acc[r];
      }
    }
  }
}

extern "C" void kernel_launch(void* const* d_in, const int* in_sizes, int n_in,
                              void* d_out, int out_size, void* d_ws, size_t ws_size,
                              hipStream_t stream) {
  (void)in_sizes; (void)n_in; (void)out_size; (void)ws_size;
  const float* x = (const float*)d_in[0];
  const int* edge_index = (const int*)d_in[1];
  const float* w_ih = (const float*)d_in[2];
  const float* w_hh = (const float*)d_in[3];
  const float* b_ih = (const float*)d_in[4];
  const float* b_hh = (const float*)d_in[5];
  const float* gc1_w = (const float*)d_in[6];
  const float* gc1_b = (const float*)d_in[7];
  const float* gc2_w = (const float*)d_in[8];
  const float* gc2_b = (const float*)d_in[9];
  const float* fc_w = (const float*)d_in[10];
  const float* fc_b = (const float*)d_in[11];
  float* out = (float*)d_out;

  // workspace layout (all regions 16B-aligned)
  char* ws = (char*)d_ws;
  _Float16* wfrag = (_Float16*)ws;                 // 12288 halves
  _Float16* l1f = wfrag + 12288;                   // 4096
  _Float16* l2f = l1f + 4096;                      // 4096
  _Float16* fcf = l2f + 4096;                      // 1024  -> 43008 B
  _Float16* hw1 = (_Float16*)(ws + 43008);         // NN*64 f16 = 6.4 MB
  _Float16* hw2 = hw1 + NN * 64;                   // NN*64 f16 = 6.4 MB
  float* dinv = (float*)(hw2 + NN * 64);           // NN f32
  int* row_start = (int*)(dinv + NN);              // 50240 ints
  int* cellbase = row_start + 50240;               // NBG+4 ints
  int* part = cellbase + NBG + 4;                  // 512 ints
  unsigned int* rec = (unsigned int*)(part + 512); // EE u32 = 6.4 MB
  unsigned short* csr = (unsigned short*)(rec + EE); // EE u16 = 3.2 MB

  const int* esrc = edge_index;
  const int* edst = edge_index + EE;

  // graph build first (gru's fused linear1 needs dinv)
  p1_frags_kernel<<<GP + 84, 256, 0, stream>>>(edst, cellbase, w_hh, gc1_w, gc2_w, fc_w, wfrag);
  scanA_kernel<<<SCB, 512, 0, stream>>>(cellbase, part);
  scanB_kernel<<<1, 512, 0, stream>>>(part);
  scanC_kernel<<<SCB, 512, 0, stream>>>(cellbase, part);
  p2_scatter_kernel<<<GP, 256, 0, stream>>>(esrc, edst, cellbase, rec);
  sort2_kernel<<<BK, 256, 0, stream>>>(rec, cellbase, csr, row_start, dinv);

  gru_kernel<<<NN / 16, 256, 0, stream>>>(x, w_ih, b_ih, b_hh, wfrag, l1f, dinv, hw1);
  agg_lin_kernel<<<BKA, 1024, 0, stream>>>(hw1, dinv, row_start, csr, gc1_b, l2f, hw2);
  agg_fc_kernel<<<BKA, 1024, 0, stream>>>(hw2, dinv, row_start, csr, gc2_b, fcf, fc_b, out);
}